// Round 5
// baseline (430.474 us; speedup 1.0000x reference)
//
#include <hip/hip_runtime.h>
#include <hip/hip_bf16.h>
#include <stdint.h>

// AdditiveAttention: B=32, S=4096, H=512, A=256
// d_out = [context: 32*512][attn: 32*4096]  (fp32)
//
// R5: ONE pass over enc; ZERO barriers in the k-loop.
//  - Stage the ENTIRE 64x512 A tile up front: 32 global float4 loads per thread
//    issued as one burst (in-order returns -> incremental vmcnt waits), cvt to
//    bf16, write LDS stash [64][520]. ONE __syncthreads.
//  - k-loop (16 steps): ds_read_b128 A-frags + MFMA + B register-ring (lead-2)
//    from L2-hot WT. No syncthreads, no vmcnt(0) drains (the R4 killer).
//  - Phase 2 context partial reads the stash (enc never re-read).

typedef __attribute__((ext_vector_type(4))) float f32x4;
typedef __attribute__((ext_vector_type(8))) short short8;

#define B_  32
#define S_  4096
#define H_  512
#define A_  256
#define CHUNKS_ 64   // 4096 / 64 rows per block

// ---- workspace layout (bytes) ----
#define WS_WT     0            // bf16 W_enc^T [256][512]   : 262144
#define WS_BIAS   262144       // fp32 [32][256]            : 32768
#define WS_SCORES 294912       // fp32 [32][4096]           : 524288
#define WS_M      819200       // fp32 [32][64]             : 8192
#define WS_L      827392       // fp32 [32][64]             : 8192
#define WS_PART   835584       // fp32 [32*64][512]         : 4194304

#define STRIDE_ 520            // stash row stride in shorts (1040 B)

static __device__ __forceinline__ short f2bf(float f) {
  union { float f; uint32_t u; } v; v.f = f;
  uint32_t r = (v.u + 0x7FFFu + ((v.u >> 16) & 1u)) >> 16;
  return (short)(uint16_t)r;
}
static __device__ __forceinline__ float bf2f(uint32_t lo16) {
  union { uint32_t u; float f; } v; v.u = lo16 << 16; return v.f;
}

// ---------------- kernel 0: prep ------------------------------------------------
__global__ __launch_bounds__(256) void prep_kernel(
    const float* __restrict__ dh, const float* __restrict__ W_enc,
    const float* __restrict__ b_enc, const float* __restrict__ W_dec,
    const float* __restrict__ b_dec, unsigned short* __restrict__ WT,
    float* __restrict__ bias) {
  __shared__ float dh_s[512];
  __shared__ unsigned short tile[64 * 66];
  const int tid = threadIdx.x;
  if (blockIdx.x < 32) {
    const int b = blockIdx.x;
    dh_s[tid]       = dh[(size_t)b * H_ + tid];
    dh_s[tid + 256] = dh[(size_t)b * H_ + tid + 256];
    __syncthreads();
    float s[4] = {0.f, 0.f, 0.f, 0.f};
    for (int k = 0; k < H_; k += 32) {
      #pragma unroll
      for (int j = 0; j < 32; ++j)
        s[j & 3] = fmaf(dh_s[k + j], W_dec[(size_t)(k + j) * A_ + tid], s[j & 3]);
    }
    bias[b * A_ + tid] = s[0] + s[1] + s[2] + s[3] + b_enc[tid] + b_dec[tid];
  } else {
    const int t = blockIdx.x - 32;          // 0..31
    const int kt = t >> 2, nt2 = t & 3;     // k-tile (8), n-tile (4)
    #pragma unroll
    for (int i = 0; i < 16; ++i) {
      int idx = tid + i * 256;
      int kk = idx >> 6, nn = idx & 63;
      tile[kk * 66 + nn] =
          (unsigned short)f2bf(W_enc[(size_t)(kt * 64 + kk) * A_ + nt2 * 64 + nn]);
    }
    __syncthreads();
    #pragma unroll
    for (int i = 0; i < 16; ++i) {
      int idx = tid + i * 256;
      int nn = idx >> 6, kk = idx & 63;
      WT[(size_t)(nt2 * 64 + nn) * H_ + kt * 64 + kk] = tile[kk * 66 + nn];
    }
  }
}

// ---------------- kernel 1: fused -----------------------------------------------
// grid 2048 = 32 b x 64 chunks of 64 rows. 4 waves; wave w owns col-tiles
// nt_g = w*4..w*4+3 (cols w*64..+63), all 4 m-tiles (rows 0..63).
__global__ __launch_bounds__(256, 2) void fused_kernel(
    const float* __restrict__ enc, const unsigned short* __restrict__ WT,
    const float* __restrict__ bias, const float* __restrict__ We,
    float* __restrict__ scores, float* __restrict__ wsm,
    float* __restrict__ wsl, float* __restrict__ part) {
  __shared__ __align__(16) unsigned short stash[64 * STRIDE_];  // 66560 B
  __shared__ float s_ps[4][64];
  __shared__ float s_e[64];

  const int tid = threadIdx.x, w = tid >> 6, lane = tid & 63;
  const int lm = lane & 15, lq = lane >> 4;
  const int b = blockIdx.x >> 6;
  const int chunk = blockIdx.x & 63;
  const int srow0 = blockIdx.x * 64;        // flat (b*S + s) row base

  // ---- A staging: thread t owns row tid>>2, k-span (tid&3)*8 (+32 per step)
  const int arow = tid >> 2, akq = (tid & 3) * 8;
  const float* aptr = enc + (size_t)(srow0 + arow) * H_ + akq;
  unsigned short* swp = &stash[arow * STRIDE_ + akq];

  // ---- B: lane's frag for nt_g = w*4+j at WT[(nt_g*16+lm)*512 + k*32 + lq*8]
  const unsigned short* bptr = WT + (size_t)((w * 4) * 16 + lm) * H_ + lq * 8;

  // ===== stage entire A tile: issue ALL 32 loads as one burst =====
  float4 buf[16][2];
  #pragma unroll
  for (int k = 0; k < 16; ++k) {
    buf[k][0] = *(const float4*)(aptr + k * 32);
    buf[k][1] = *(const float4*)(aptr + k * 32 + 4);
  }
  // B ring slots 0,1 in flight during the cvt/write phase (L2-hot)
  short8 Bring[3][4];
  #pragma unroll
  for (int j = 0; j < 4; ++j) {
    Bring[0][j] = *(const short8*)(bptr + (size_t)j * 16 * H_);
    Bring[1][j] = *(const short8*)(bptr + (size_t)j * 16 * H_ + 32);
  }
  #pragma unroll
  for (int k = 0; k < 16; ++k) {
    short8 sv;
    sv[0] = f2bf(buf[k][0].x); sv[1] = f2bf(buf[k][0].y);
    sv[2] = f2bf(buf[k][0].z); sv[3] = f2bf(buf[k][0].w);
    sv[4] = f2bf(buf[k][1].x); sv[5] = f2bf(buf[k][1].y);
    sv[6] = f2bf(buf[k][1].z); sv[7] = f2bf(buf[k][1].w);
    *(short8*)(swp + k * 32) = sv;
  }
  __syncthreads();                          // the ONLY k-path barrier

  f32x4 acc[4][4];
  #pragma unroll
  for (int mt = 0; mt < 4; ++mt)
    #pragma unroll
    for (int j = 0; j < 4; ++j)
      acc[mt][j] = (f32x4){0.f, 0.f, 0.f, 0.f};

  // ===== k-loop: NO barriers =====
  #pragma unroll
  for (int k = 0; k < 16; ++k) {
    if (k + 2 < 16) {
      #pragma unroll
      for (int j = 0; j < 4; ++j)
        Bring[(k + 2) % 3][j] =
            *(const short8*)(bptr + (size_t)j * 16 * H_ + (k + 2) * 32);
    }
    #pragma unroll
    for (int mt = 0; mt < 4; ++mt) {
      short8 af = *(const short8*)&stash[(mt * 16 + lm) * STRIDE_ + k * 32 + lq * 8];
      #pragma unroll
      for (int j = 0; j < 4; ++j)
        acc[mt][j] = __builtin_amdgcn_mfma_f32_16x16x32_bf16(af, Bring[k % 3][j], acc[mt][j], 0, 0, 0);
    }
  }

  // ---- epilogue: per-wave partial score over its 64 cols ----
  // C/D: col = (w*4+j)*16 + lm, row(in mt) = lq*4 + r
  float psum[4][4] = {{0,0,0,0},{0,0,0,0},{0,0,0,0},{0,0,0,0}};
  #pragma unroll
  for (int j = 0; j < 4; ++j) {
    const int col = (w * 4 + j) * 16 + lm;
    const float dp = bias[b * A_ + col];
    const float wv = We[col];
    #pragma unroll
    for (int mt = 0; mt < 4; ++mt)
      #pragma unroll
      for (int r = 0; r < 4; ++r) {
        float x = acc[mt][j][r] + dp;
        float e = __expf(2.0f * x);
        float t = 1.0f - 2.0f * __builtin_amdgcn_rcpf(e + 1.0f);
        psum[mt][r] = fmaf(t, wv, psum[mt][r]);
      }
  }
  #pragma unroll
  for (int o = 1; o < 16; o <<= 1)
    #pragma unroll
    for (int mt = 0; mt < 4; ++mt)
      #pragma unroll
      for (int r = 0; r < 4; ++r)
        psum[mt][r] += __shfl_xor(psum[mt][r], o, 64);
  if (lm == 0) {
    #pragma unroll
    for (int mt = 0; mt < 4; ++mt)
      #pragma unroll
      for (int r = 0; r < 4; ++r)
        s_ps[w][mt * 16 + lq * 4 + r] = psum[mt][r];
  }
  __syncthreads();

  // ---- cross-wave sum, chunk softmax (wave 0) ----
  if (tid < 64) {
    const float sc = s_ps[0][tid] + s_ps[1][tid] + s_ps[2][tid] + s_ps[3][tid];
    scores[srow0 + tid] = sc;
    float m = sc;
    #pragma unroll
    for (int o = 1; o < 64; o <<= 1) m = fmaxf(m, __shfl_xor(m, o, 64));
    const float e = __expf(sc - m);
    float l = e;
    #pragma unroll
    for (int o = 1; o < 64; o <<= 1) l += __shfl_xor(l, o, 64);
    s_e[tid] = e;
    if (tid == 0) {
      wsm[b * CHUNKS_ + chunk] = m;
      wsl[b * CHUNKS_ + chunk] = l;
    }
  }
  __syncthreads();

  // ---- phase 2: context partial from LDS stash ----
  float cx0 = 0.f, cx1 = 0.f;
  #pragma unroll 8
  for (int row = 0; row < 64; ++row) {
    uint32_t pv = *(const uint32_t*)&stash[row * STRIDE_ + (tid << 1)];
    float wr = s_e[row];
    cx0 = fmaf(wr, bf2f(pv & 0xffffu), cx0);
    cx1 = fmaf(wr, bf2f(pv >> 16), cx1);
  }
  float2 o2; o2.x = cx0; o2.y = cx1;
  *(float2*)&part[(size_t)(b * CHUNKS_ + chunk) * H_ + (tid << 1)] = o2;
}

// ---------------- kernel 2: finalize --------------------------------------------
__global__ __launch_bounds__(256) void finalize_kernel(
    const float* __restrict__ scores, const float* __restrict__ wsm,
    const float* __restrict__ wsl, const float* __restrict__ part,
    float* __restrict__ ctx, float* __restrict__ attn) {
  __shared__ float wgt[CHUNKS_];
  __shared__ float s_ml[2];
  const int b = blockIdx.x, tid = threadIdx.x;
  if (tid < 64) {
    float mc = wsm[b * CHUNKS_ + tid];
    float lc = wsl[b * CHUNKS_ + tid];
    float M = mc;
    #pragma unroll
    for (int o = 1; o < 64; o <<= 1) M = fmaxf(M, __shfl_xor(M, o, 64));
    float wv = __expf(mc - M);
    float Lp = wv * lc;
    #pragma unroll
    for (int o = 1; o < 64; o <<= 1) Lp += __shfl_xor(Lp, o, 64);
    wgt[tid] = wv;
    if (tid == 0) { s_ml[0] = M; s_ml[1] = Lp; }
  }
  __syncthreads();
  const float M = s_ml[0];
  const float invL = 1.0f / s_ml[1];

  #pragma unroll
  for (int hh = 0; hh < 2; ++hh) {
    const int h = tid + hh * 256;
    float s = 0.f;
    #pragma unroll 8
    for (int c = 0; c < CHUNKS_; ++c)
      s = fmaf(wgt[c], part[(size_t)(b * CHUNKS_ + c) * H_ + h], s);
    ctx[(size_t)b * H_ + h] = s * invL;
  }
  #pragma unroll
  for (int i = 0; i < 16; ++i) {
    const int s_ = tid + i * 256;
    attn[(size_t)b * S_ + s_] = __expf(scores[(size_t)b * S_ + s_] - M) * invL;
  }
}

extern "C" void kernel_launch(void* const* d_in, const int* in_sizes, int n_in,
                              void* d_out, int out_size, void* d_ws, size_t ws_size,
                              hipStream_t stream) {
  const float* enc   = (const float*)d_in[0];
  const float* dh    = (const float*)d_in[1];
  const float* W_enc = (const float*)d_in[2];
  const float* b_enc = (const float*)d_in[3];
  const float* W_dec = (const float*)d_in[4];
  const float* b_dec = (const float*)d_in[5];
  const float* W_e   = (const float*)d_in[6];
  // b_e (d_in[7]) dropped: softmax is shift-invariant, scores not an output.

  char* ws = (char*)d_ws;
  unsigned short* WT = (unsigned short*)(ws + WS_WT);
  float* bias   = (float*)(ws + WS_BIAS);
  float* scores = (float*)(ws + WS_SCORES);
  float* wsm    = (float*)(ws + WS_M);
  float* wsl    = (float*)(ws + WS_L);
  float* part   = (float*)(ws + WS_PART);

  float* ctx  = (float*)d_out;            // [32][512]
  float* attn = (float*)d_out + B_ * H_;  // [32][4096]

  prep_kernel<<<dim3(64), dim3(256), 0, stream>>>(dh, W_enc, b_enc, W_dec, b_dec, WT, bias);
  fused_kernel<<<dim3(2048), dim3(256), 0, stream>>>(enc, WT, bias, W_e, scores, wsm, wsl, part);
  finalize_kernel<<<dim3(32), dim3(256), 0, stream>>>(scores, wsm, wsl, part, ctx, attn);
}